// Round 8
// baseline (149.360 us; speedup 1.0000x reference)
//
#include <hip/hip_runtime.h>
#include <stdint.h>

#define B_ROWS 32768
#define N_INP 256
#define N_HID 1024
#define NF 256
#define N_IT 100

typedef __attribute__((ext_vector_type(8))) _Float16 f16x8;
typedef __attribute__((ext_vector_type(4))) float f32x4;

__device__ __forceinline__ ushort f2h(float f) {
  _Float16 h = (_Float16)f;               // v_cvt_f16_f32, RNE
  return *reinterpret_cast<ushort*>(&h);
}

__device__ __forceinline__ void async_copy16(const void* g, void* l) {
  __builtin_amdgcn_global_load_lds(
      (const __attribute__((address_space(1))) void*)g,
      (__attribute__((address_space(3))) void*)l, 16, 0, 0);
}

// ---- prepass (fused): pack x -> f16 [B,256] + idx; convert W1/W2 -> f16 ----
__global__ void prep_kernel(const float* __restrict__ x,
                            const float* __restrict__ W1,
                            const float* __restrict__ W2,
                            ushort* __restrict__ xh,
                            ushort* __restrict__ w1h,
                            ushort* __restrict__ w2h,
                            int* __restrict__ idx) {
  if (blockIdx.x < 8192) {
    int t = blockIdx.x * 256 + threadIdx.x;          // B*64 threads
    int b = t >> 6, q = t & 63;
    const float* xr = x + (size_t)b * (N_INP + 1);
    float v0 = xr[q * 4 + 0], v1 = xr[q * 4 + 1], v2 = xr[q * 4 + 2], v3 = xr[q * 4 + 3];
    ushort4 u = make_ushort4(f2h(v0), f2h(v1), f2h(v2), f2h(v3));
    *reinterpret_cast<ushort4*>(xh + (size_t)b * 256 + q * 4) = u;
    if (q == 0) idx[b] = (int)rintf(xr[N_INP] * 255.0f);
  } else {
    int t = (blockIdx.x - 8192) * 256 + threadIdx.x; // 65536 threads
    float4 a = reinterpret_cast<const float4*>(W1)[t];
    float4 b = reinterpret_cast<const float4*>(W2)[t];
    reinterpret_cast<ushort4*>(w1h)[t] = make_ushort4(f2h(a.x), f2h(a.y), f2h(a.z), f2h(a.w));
    reinterpret_cast<ushort4*>(w2h)[t] = make_ushort4(f2h(b.x), f2h(b.y), f2h(b.z), f2h(b.w));
  }
}

// ---- GEMM1: h = relu(xh @ W1^T + b1), f16 output (unchanged, proven) ----
template <int RELU>
__global__ __launch_bounds__(256, 2) void gemm_bt(
    const ushort* __restrict__ A, const ushort* __restrict__ Bw,
    const float* __restrict__ bias, ushort* __restrict__ C,
    int M, int N, int K, int ntN) {
  __shared__ ushort As[2][128 * 64];
  __shared__ ushort Bs[2][128 * 64];
  const int tid = threadIdx.x;
  const int w = tid >> 6, l = tid & 63;
  int bid = blockIdx.x;
  if (((int)gridDim.x & 7) == 0) {
    int cpx = (int)gridDim.x >> 3;
    bid = (bid & 7) * cpx + (bid >> 3);
  }
  const int tm = bid / ntN, tn = bid % ntN;
  const int wm = w >> 1, wn = w & 1;
  const char* Ab = (const char*)(A + (size_t)tm * 128 * K);
  const char* Bb = (const char*)(Bw + (size_t)tn * 128 * K);
  const int sA = K * 2;
  const int lrow = l >> 3;
  const int lcol = (l & 7) * 16;

  f32x4 acc[4][4];
#pragma unroll
  for (int i = 0; i < 4; ++i)
#pragma unroll
    for (int j = 0; j < 4; ++j) acc[i][j] = {0.f, 0.f, 0.f, 0.f};

  const int nkt = K / 64;
  {
    const char* ga = Ab + lrow * sA + lcol;
    const char* gb = Bb + lrow * sA + lcol;
#pragma unroll
    for (int i = 0; i < 4; ++i) {
      int c = w * 4 + i;
      async_copy16(ga + c * 8 * sA, (char*)&As[0][0] + c * 1024);
      async_copy16(gb + c * 8 * sA, (char*)&Bs[0][0] + c * 1024);
    }
  }
  __syncthreads();

  const int arow = wm * 64 + (l & 15);
  const int brow = wn * 64 + (l & 15);
  const int koff = (l >> 4) * 8;

  for (int kt = 0; kt < nkt; ++kt) {
    const int buf = kt & 1;
    if (kt + 1 < nkt) {
      const char* ga = Ab + (kt + 1) * 128 + lrow * sA + lcol;
      const char* gb = Bb + (kt + 1) * 128 + lrow * sA + lcol;
#pragma unroll
      for (int i = 0; i < 4; ++i) {
        int c = w * 4 + i;
        async_copy16(ga + c * 8 * sA, (char*)&As[buf ^ 1][0] + c * 1024);
        async_copy16(gb + c * 8 * sA, (char*)&Bs[buf ^ 1][0] + c * 1024);
      }
    }
#pragma unroll
    for (int ks = 0; ks < 2; ++ks) {
      f16x8 af[4], bfr[4];
#pragma unroll
      for (int mi = 0; mi < 4; ++mi)
        af[mi] = *(const f16x8*)&As[buf][(arow + mi * 16) * 64 + ks * 32 + koff];
#pragma unroll
      for (int ni = 0; ni < 4; ++ni)
        bfr[ni] = *(const f16x8*)&Bs[buf][(brow + ni * 16) * 64 + ks * 32 + koff];
#pragma unroll
      for (int mi = 0; mi < 4; ++mi)
#pragma unroll
        for (int ni = 0; ni < 4; ++ni)
          acc[mi][ni] = __builtin_amdgcn_mfma_f32_16x16x32_f16(
              af[mi], bfr[ni], acc[mi][ni], 0, 0, 0);
    }
    __syncthreads();
  }

  const int grow0 = tm * 128 + wm * 64 + (l >> 4) * 4;
  const int gcol0 = tn * 128 + wn * 64 + (l & 15);
#pragma unroll
  for (int ni = 0; ni < 4; ++ni) {
    const int col = gcol0 + ni * 16;
    const float bv = bias[col];
#pragma unroll
    for (int mi = 0; mi < 4; ++mi) {
      const int row = grow0 + mi * 16;
#pragma unroll
      for (int r = 0; r < 4; ++r) {
        float v = acc[mi][ni][r] + bv;
        if (RELU) v = fmaxf(v, 0.f);
        C[(size_t)(row + r) * N + col] = f2h(v);
      }
    }
  }
}

// ---- FUSED: x_ tile = h @ W2^T + b2 (f32, stays in LDS) -> 100-iter convex
//      (in registers, ping-pong Jacobi) -> gather -> out.  64 rows/block.
// LDS: As 2x[64][64] f16 (16K) + Bs 2x[256][64] f16 (64K) = 80K; after the
// K-loop the same memory is reused as yf[64][256] f32 (64K). 2 blocks/CU.
__global__ __launch_bounds__(1024, 4) void gemm2_convex(
    const ushort* __restrict__ A,      // h chunk [curM][1024] f16
    const ushort* __restrict__ Bw,     // w2h [256][1024] f16
    const float* __restrict__ bias,    // b2 [256] f32
    const int* __restrict__ idx,       // idx + m0
    float* __restrict__ out) {         // out + m0
  __shared__ char smem[81920];
  ushort* AsU = (ushort*)smem;                 // 2 bufs x 8192 B
  ushort* BsU = (ushort*)(smem + 16384);       // 2 bufs x 32768 B
  float* yf = (float*)smem;                    // [64][256] f32 (aliased)

  const int tid = threadIdx.x;
  const int w = tid >> 6, l = tid & 63;
  const int wm = w >> 2, wn = w & 3;           // 4x4 wave grid
  const int m0r = blockIdx.x * 64;

  const char* Ab = (const char*)(A + (size_t)m0r * N_HID);
  const char* Bb = (const char*)Bw;

  f32x4 acc[4];
#pragma unroll
  for (int i = 0; i < 4; ++i) acc[i] = {0.f, 0.f, 0.f, 0.f};

  // stage k-step kt into buffer buf: A 8 wave-loads, B 32 wave-loads,
  // distributed over 16 waves (slots w, w+16, w+32; skip >= 40)
#define STAGE(kt, buf)                                                      \
  {                                                                         \
    _Pragma("unroll") for (int i = 0; i < 3; ++i) {                         \
      int s = w + i * 16;                                                   \
      if (s < 8) {                                                          \
        const char* g = Ab + (size_t)(s * 8 + (l >> 3)) * 2048 +            \
                        (kt) * 128 + (l & 7) * 16;                          \
        async_copy16(g, smem + (buf) * 8192 + s * 1024 + l * 16);           \
      } else if (s < 40) {                                                  \
        const char* g = Bb + (size_t)((s - 8) * 8 + (l >> 3)) * 2048 +      \
                        (kt) * 128 + (l & 7) * 16;                          \
        async_copy16(g, smem + 16384 + (buf) * 32768 + (s - 8) * 1024 +     \
                     l * 16);                                               \
      }                                                                     \
    }                                                                       \
  }

  STAGE(0, 0);
  __syncthreads();

  const int koff = (l >> 4) * 8;
  const int ar = wm * 16 + (l & 15);

  for (int kt = 0; kt < 16; ++kt) {
    const int buf = kt & 1;
    if (kt < 15) STAGE(kt + 1, buf ^ 1);
#pragma unroll
    for (int ks = 0; ks < 2; ++ks) {
      f16x8 af = *(const f16x8*)(AsU + buf * 4096 + ar * 64 + ks * 32 + koff);
      f16x8 bfr[4];
#pragma unroll
      for (int ni = 0; ni < 4; ++ni) {
        int br = wn * 64 + ni * 16 + (l & 15);
        bfr[ni] = *(const f16x8*)(BsU + buf * 16384 + br * 64 + ks * 32 + koff);
      }
#pragma unroll
      for (int ni = 0; ni < 4; ++ni)
        acc[ni] = __builtin_amdgcn_mfma_f32_16x16x32_f16(af, bfr[ni], acc[ni], 0, 0, 0);
    }
    __syncthreads();
  }
#undef STAGE

  // epilogue: write f32 x_ tile into LDS (aliases staging bufs; all reads done)
  {
    const int r0 = wm * 16 + (l >> 4) * 4;
    const int c0 = wn * 64 + (l & 15);
#pragma unroll
    for (int ni = 0; ni < 4; ++ni) {
      const int col = c0 + ni * 16;
      const float bv = bias[col];
#pragma unroll
      for (int r = 0; r < 4; ++r) yf[(r0 + r) * 256 + col] = acc[ni][r] + bv;
    }
  }
  __syncthreads();

  // ---- convex: 16 lanes/row, 16 feats/lane, ping-pong Jacobi ----
  const int row = w * 4 + (l >> 4);    // 0..63
  const int q = l & 15;
  float y[16], z[16];
  {
    const float* src = yf + row * 256 + q * 16;
#pragma unroll
    for (int j = 0; j < 4; ++j) {
      float4 v = *reinterpret_cast<const float4*>(src + j * 4);
      y[j * 4 + 0] = v.x; y[j * 4 + 1] = v.y; y[j * 4 + 2] = v.z; y[j * 4 + 3] = v.w;
    }
  }
  const int ii = idx[m0r + row];
  const int upIdx = ((l - 1) & 63) * 4;
  const int dnIdx = ((l + 1) & 63) * 4;
  const float bL = (q == 0) ? 3.0e38f : 0.0f;   // feat 0 never drops
  const float bR = (q == 15) ? 3.0e38f : 0.0f;  // feat 255 never drops

  for (int it = 0; it < N_IT / 2; ++it) {
    {
      float Lv = __int_as_float(__builtin_amdgcn_ds_bpermute(upIdx, __float_as_int(y[15]))) + bL;
      float Rv = __int_as_float(__builtin_amdgcn_ds_bpermute(dnIdx, __float_as_int(y[0]))) + bR;
      z[0] = fminf(y[0], 0.5f * (Lv + y[1]));
#pragma unroll
      for (int t = 1; t < 15; ++t) z[t] = fminf(y[t], 0.5f * (y[t - 1] + y[t + 1]));
      z[15] = fminf(y[15], 0.5f * (y[14] + Rv));
    }
    {
      float Lv = __int_as_float(__builtin_amdgcn_ds_bpermute(upIdx, __float_as_int(z[15]))) + bL;
      float Rv = __int_as_float(__builtin_amdgcn_ds_bpermute(dnIdx, __float_as_int(z[0]))) + bR;
      y[0] = fminf(z[0], 0.5f * (Lv + z[1]));
#pragma unroll
      for (int t = 1; t < 15; ++t) y[t] = fminf(z[t], 0.5f * (z[t - 1] + z[t + 1]));
      y[15] = fminf(z[15], 0.5f * (z[14] + Rv));
    }
  }

  // gather feature ii: cndmask tree over 16 regs, then cross-lane pick
  const int sel = ii & 15;
#pragma unroll
  for (int step = 8; step >= 1; step >>= 1) {
#pragma unroll
    for (int k = 0; k < 8; ++k) {
      if (k < step) y[k] = (sel & step) ? y[k + step] : y[k];
    }
  }
  float v = __shfl(y[0], (l & ~15) | (ii >> 4));
  if (q == 0) out[m0r + row] = v;
}

extern "C" void kernel_launch(void* const* d_in, const int* in_sizes, int n_in,
                              void* d_out, int out_size, void* d_ws, size_t ws_size,
                              hipStream_t stream) {
  const float* x = (const float*)d_in[0];
  const float* W1 = (const float*)d_in[1];
  const float* b1 = (const float*)d_in[2];
  const float* W2 = (const float*)d_in[3];
  const float* b2 = (const float*)d_in[4];
  float* out = (float*)d_out;

  // workspace layout (16B-aligned)
  char* ws = (char*)d_ws;
  ushort* xh  = (ushort*)ws;                    // 16,777,216 B  x f16 [B,256]
  ushort* w1h = (ushort*)(ws + 16777216);       //    524,288 B
  ushort* w2h = (ushort*)(ws + 17301504);       //    524,288 B
  int*    idx = (int*)  (ws + 17825792);        //    131,072 B
  ushort* h   = (ushort*)(ws + 17956864);       // chunk*2048 B  h f16 [chunk,1024]

  const size_t fixed = 17956864;
  int chunk = 2048;
  if (ws_size >= fixed + (size_t)32768 * 2048) chunk = 32768;
  else if (ws_size >= fixed + (size_t)16384 * 2048) chunk = 16384;
  else if (ws_size >= fixed + (size_t)8192 * 2048) chunk = 8192;
  else if (ws_size >= fixed + (size_t)4096 * 2048) chunk = 4096;

  prep_kernel<<<8448, 256, 0, stream>>>(x, W1, W2, xh, w1h, w2h, idx);

  for (int m0 = 0; m0 < B_ROWS; m0 += chunk) {
    int curM = (B_ROWS - m0 < chunk) ? (B_ROWS - m0) : chunk;
    dim3 g1((curM / 128) * (N_HID / 128));
    gemm_bt<1><<<g1, 256, 0, stream>>>(xh + (size_t)m0 * 256, w1h, b1, h,
                                       curM, N_HID, N_INP, N_HID / 128);
    gemm2_convex<<<curM / 64, 1024, 0, stream>>>(h, w2h, b2, idx + m0, out + m0);
  }
}

// Round 9
// 136.071 us; speedup vs baseline: 1.0977x; 1.0977x over previous
//
#include <hip/hip_runtime.h>
#include <stdint.h>

#define B_ROWS 32768
#define N_INP 256
#define N_HID 1024
#define NF 256
#define N_IT 100

typedef __attribute__((ext_vector_type(8))) _Float16 f16x8;
typedef __attribute__((ext_vector_type(4))) float f32x4;

__device__ __forceinline__ ushort f2h(float f) {
  _Float16 h = (_Float16)f;               // v_cvt_f16_f32, RNE
  return *reinterpret_cast<ushort*>(&h);
}

__device__ __forceinline__ void async_copy16(const void* g, void* l) {
  __builtin_amdgcn_global_load_lds(
      (const __attribute__((address_space(1))) void*)g,
      (__attribute__((address_space(3))) void*)l, 16, 0, 0);
}

// ---- prepass (fused): pack x -> f16 [B,256] + idx; convert W1/W2 -> f16 ----
__global__ void prep_kernel(const float* __restrict__ x,
                            const float* __restrict__ W1,
                            const float* __restrict__ W2,
                            ushort* __restrict__ xh,
                            ushort* __restrict__ w1h,
                            ushort* __restrict__ w2h,
                            int* __restrict__ idx) {
  if (blockIdx.x < 8192) {
    int t = blockIdx.x * 256 + threadIdx.x;          // B*64 threads
    int b = t >> 6, q = t & 63;
    const float* xr = x + (size_t)b * (N_INP + 1);
    float v0 = xr[q * 4 + 0], v1 = xr[q * 4 + 1], v2 = xr[q * 4 + 2], v3 = xr[q * 4 + 3];
    ushort4 u = make_ushort4(f2h(v0), f2h(v1), f2h(v2), f2h(v3));
    *reinterpret_cast<ushort4*>(xh + (size_t)b * 256 + q * 4) = u;
    if (q == 0) idx[b] = (int)rintf(xr[N_INP] * 255.0f);
  } else {
    int t = (blockIdx.x - 8192) * 256 + threadIdx.x; // 65536 threads
    float4 a = reinterpret_cast<const float4*>(W1)[t];
    float4 b = reinterpret_cast<const float4*>(W2)[t];
    reinterpret_cast<ushort4*>(w1h)[t] = make_ushort4(f2h(a.x), f2h(a.y), f2h(a.z), f2h(a.w));
    reinterpret_cast<ushort4*>(w2h)[t] = make_ushort4(f2h(b.x), f2h(b.y), f2h(b.z), f2h(b.w));
  }
}

// ---- C[M,N] = epi(A[M,K] @ Bw[N,K]^T + bias), f16 output ----
template <int RELU>
__global__ __launch_bounds__(256, 2) void gemm_bt(
    const ushort* __restrict__ A, const ushort* __restrict__ Bw,
    const float* __restrict__ bias, ushort* __restrict__ C,
    int M, int N, int K, int ntN) {
  __shared__ ushort As[2][128 * 64];
  __shared__ ushort Bs[2][128 * 64];
  const int tid = threadIdx.x;
  const int w = tid >> 6, l = tid & 63;
  // bijective XCD swizzle (grid%8==0 in all our launches)
  int bid = blockIdx.x;
  if (((int)gridDim.x & 7) == 0) {
    int cpx = (int)gridDim.x >> 3;
    bid = (bid & 7) * cpx + (bid >> 3);
  }
  const int tm = bid / ntN, tn = bid % ntN;
  const int wm = w >> 1, wn = w & 1;
  const char* Ab = (const char*)(A + (size_t)tm * 128 * K);
  const char* Bb = (const char*)(Bw + (size_t)tn * 128 * K);
  const int sA = K * 2;
  const int lrow = l >> 3;
  const int lcol = (l & 7) * 16;

  f32x4 acc[4][4];
#pragma unroll
  for (int i = 0; i < 4; ++i)
#pragma unroll
    for (int j = 0; j < 4; ++j) acc[i][j] = {0.f, 0.f, 0.f, 0.f};

  const int nkt = K / 64;
  {
    const char* ga = Ab + lrow * sA + lcol;
    const char* gb = Bb + lrow * sA + lcol;
#pragma unroll
    for (int i = 0; i < 4; ++i) {
      int c = w * 4 + i;
      async_copy16(ga + c * 8 * sA, (char*)&As[0][0] + c * 1024);
      async_copy16(gb + c * 8 * sA, (char*)&Bs[0][0] + c * 1024);
    }
  }
  __syncthreads();

  const int arow = wm * 64 + (l & 15);
  const int brow = wn * 64 + (l & 15);
  const int koff = (l >> 4) * 8;

  for (int kt = 0; kt < nkt; ++kt) {
    const int buf = kt & 1;
    if (kt + 1 < nkt) {
      const char* ga = Ab + (kt + 1) * 128 + lrow * sA + lcol;
      const char* gb = Bb + (kt + 1) * 128 + lrow * sA + lcol;
#pragma unroll
      for (int i = 0; i < 4; ++i) {
        int c = w * 4 + i;
        async_copy16(ga + c * 8 * sA, (char*)&As[buf ^ 1][0] + c * 1024);
        async_copy16(gb + c * 8 * sA, (char*)&Bs[buf ^ 1][0] + c * 1024);
      }
    }
#pragma unroll
    for (int ks = 0; ks < 2; ++ks) {
      f16x8 af[4], bfr[4];
#pragma unroll
      for (int mi = 0; mi < 4; ++mi)
        af[mi] = *(const f16x8*)&As[buf][(arow + mi * 16) * 64 + ks * 32 + koff];
#pragma unroll
      for (int ni = 0; ni < 4; ++ni)
        bfr[ni] = *(const f16x8*)&Bs[buf][(brow + ni * 16) * 64 + ks * 32 + koff];
#pragma unroll
      for (int mi = 0; mi < 4; ++mi)
#pragma unroll
        for (int ni = 0; ni < 4; ++ni)
          acc[mi][ni] = __builtin_amdgcn_mfma_f32_16x16x32_f16(
              af[mi], bfr[ni], acc[mi][ni], 0, 0, 0);
    }
    __syncthreads();
  }

  const int grow0 = tm * 128 + wm * 64 + (l >> 4) * 4;
  const int gcol0 = tn * 128 + wn * 64 + (l & 15);
#pragma unroll
  for (int ni = 0; ni < 4; ++ni) {
    const int col = gcol0 + ni * 16;
    const float bv = bias[col];
#pragma unroll
    for (int mi = 0; mi < 4; ++mi) {
      const int row = grow0 + mi * 16;
#pragma unroll
      for (int r = 0; r < 4; ++r) {
        float v = acc[mi][ni][r] + bv;
        if (RELU) v = fmaxf(v, 0.f);
        C[(size_t)(row + r) * N + col] = f2h(v);
      }
    }
  }
}

// ---- convex fixed-point (100 iters) + gather ----
// y-space: y_i <- min(y_i, 0.5*(y_{i-1}+y_{i+1})); result = y.
// 16 lanes/row, 16 feats/lane, ping-pong y/z Jacobi.
// ANTI-CONVOY: boundary feats (15, 0) computed FIRST each half-step, next
// half-step's bpermutes issued immediately on them, interior feats 1..14
// (42 VALU ~ 84 cyc) computed under the DS latency, shuffle results
// consumed only at the very end -> lgkmcnt wait is off the critical path.
__global__ __launch_bounds__(256) void convex_gather(
    const ushort* __restrict__ xqh, const int* __restrict__ idx,
    float* __restrict__ out) {
  const int l = threadIdx.x & 63;
  const int wv = threadIdx.x >> 6;
  const int q = l & 15;                                // lane within row
  const int b = blockIdx.x * 16 + wv * 4 + (l >> 4);   // global row

  float y[16], z[16];
  {
    const ushort* src = xqh + (size_t)b * 256 + q * 16;
    f16x8 h0 = *reinterpret_cast<const f16x8*>(src);
    f16x8 h1 = *reinterpret_cast<const f16x8*>(src + 8);
#pragma unroll
    for (int j = 0; j < 8; ++j) {
      y[j] = (float)h0[j];
      y[8 + j] = (float)h1[j];
    }
  }
  const int ii = idx[b];
  const int upIdx = ((l - 1) & 63) * 4;
  const int dnIdx = ((l + 1) & 63) * 4;
  const float bL = (q == 0) ? 3.0e38f : 0.0f;   // feat 0 never drops
  const float bR = (q == 15) ? 3.0e38f : 0.0f;  // feat 255 never drops

  // prologue: neighbor values for iteration 0
  float Lv = __int_as_float(
                 __builtin_amdgcn_ds_bpermute(upIdx, __float_as_int(y[15]))) + bL;
  float Rv = __int_as_float(
                 __builtin_amdgcn_ds_bpermute(dnIdx, __float_as_int(y[0]))) + bR;

#define HALF_STEP(S, D)                                                       \
  {                                                                           \
    D[15] = fminf(S[15], 0.5f * (S[14] + Rv));                                \
    D[0] = fminf(S[0], 0.5f * (Lv + S[1]));                                   \
    int nl_ = __builtin_amdgcn_ds_bpermute(upIdx, __float_as_int(D[15]));     \
    int nr_ = __builtin_amdgcn_ds_bpermute(dnIdx, __float_as_int(D[0]));      \
    _Pragma("unroll") for (int t = 1; t < 15; ++t)                            \
        D[t] = fminf(S[t], 0.5f * (S[t - 1] + S[t + 1]));                     \
    Lv = __int_as_float(nl_) + bL;                                            \
    Rv = __int_as_float(nr_) + bR;                                            \
  }

  for (int it = 0; it < N_IT / 2; ++it) {
    HALF_STEP(y, z);
    HALF_STEP(z, y);
  }
#undef HALF_STEP

  // gather feature ii: cndmask tree over 16 regs, then cross-lane pick
  const int sel = ii & 15;
#pragma unroll
  for (int step = 8; step >= 1; step >>= 1) {
#pragma unroll
    for (int k = 0; k < 8; ++k) {
      if (k < step) y[k] = (sel & step) ? y[k + step] : y[k];
    }
  }
  float v = __shfl(y[0], (l & ~15) | (ii >> 4));
  if (q == 0) out[b] = v;
}

extern "C" void kernel_launch(void* const* d_in, const int* in_sizes, int n_in,
                              void* d_out, int out_size, void* d_ws, size_t ws_size,
                              hipStream_t stream) {
  const float* x = (const float*)d_in[0];
  const float* W1 = (const float*)d_in[1];
  const float* b1 = (const float*)d_in[2];
  const float* W2 = (const float*)d_in[3];
  const float* b2 = (const float*)d_in[4];
  float* out = (float*)d_out;

  // workspace layout (16B-aligned)
  char* ws = (char*)d_ws;
  ushort* xh  = (ushort*)ws;                    // 16,777,216 B  x f16 [B,256]
  ushort* w1h = (ushort*)(ws + 16777216);       //    524,288 B
  ushort* w2h = (ushort*)(ws + 17301504);       //    524,288 B
  int*    idx = (int*)  (ws + 17825792);        //    131,072 B
  ushort* xqh = (ushort*)(ws + 17956864);       // 16,777,216 B  x_ f16 [B,256]
  ushort* h   = (ushort*)(ws + 34734080);       // chunk*2048 B  h f16 [chunk,1024]

  const size_t fixed = 34734080;
  int chunk = 2048;
  if (ws_size >= fixed + (size_t)32768 * 2048) chunk = 32768;
  else if (ws_size >= fixed + (size_t)16384 * 2048) chunk = 16384;
  else if (ws_size >= fixed + (size_t)8192 * 2048) chunk = 8192;
  else if (ws_size >= fixed + (size_t)4096 * 2048) chunk = 4096;

  prep_kernel<<<8448, 256, 0, stream>>>(x, W1, W2, xh, w1h, w2h, idx);

  for (int m0 = 0; m0 < B_ROWS; m0 += chunk) {
    int curM = (B_ROWS - m0 < chunk) ? (B_ROWS - m0) : chunk;
    dim3 g1((curM / 128) * (N_HID / 128));
    gemm_bt<1><<<g1, 256, 0, stream>>>(xh + (size_t)m0 * 256, w1h, b1, h,
                                       curM, N_HID, N_INP, N_HID / 128);
    dim3 g2((curM / 128) * (NF / 128));
    gemm_bt<0><<<g2, 256, 0, stream>>>(h, w2h, b2, xqh + (size_t)m0 * 256,
                                       curM, NF, N_HID, NF / 128);
  }
  convex_gather<<<B_ROWS / 16, 256, 0, stream>>>(xqh, idx, out);
}

// Round 10
// 133.694 us; speedup vs baseline: 1.1172x; 1.0178x over previous
//
#include <hip/hip_runtime.h>
#include <stdint.h>

#define B_ROWS 32768
#define N_INP 256
#define N_HID 1024
#define NF 256
#define N_IT 100

typedef __attribute__((ext_vector_type(8))) _Float16 f16x8;
typedef __attribute__((ext_vector_type(4))) float f32x4;
typedef __attribute__((ext_vector_type(2))) _Float16 f16x2;
typedef uint32_t u32;

__device__ __forceinline__ ushort f2h(float f) {
  _Float16 h = (_Float16)f;               // v_cvt_f16_f32, RNE
  return *reinterpret_cast<ushort*>(&h);
}

__device__ __forceinline__ void async_copy16(const void* g, void* l) {
  __builtin_amdgcn_global_load_lds(
      (const __attribute__((address_space(1))) void*)g,
      (__attribute__((address_space(3))) void*)l, 16, 0, 0);
}

__device__ __forceinline__ f16x2 as_h2(u32 x) { return __builtin_bit_cast(f16x2, x); }
__device__ __forceinline__ u32 as_u32(f16x2 x) { return __builtin_bit_cast(u32, x); }
// packed f16 min (VOP3P, full rate). Single 32-bit operand per constraint ->
// no register-pair tying (R7's asm-pair regalloc failure mode doesn't apply).
__device__ __forceinline__ f16x2 min2(f16x2 a, f16x2 b) {
  f16x2 r;
  asm("v_pk_min_f16 %0, %1, %2" : "=v"(r) : "v"(a), "v"(b));
  return r;
}

// ---- prepass (fused): pack x -> f16 [B,256] + idx; convert W1/W2 -> f16 ----
__global__ void prep_kernel(const float* __restrict__ x,
                            const float* __restrict__ W1,
                            const float* __restrict__ W2,
                            ushort* __restrict__ xh,
                            ushort* __restrict__ w1h,
                            ushort* __restrict__ w2h,
                            int* __restrict__ idx) {
  if (blockIdx.x < 8192) {
    int t = blockIdx.x * 256 + threadIdx.x;          // B*64 threads
    int b = t >> 6, q = t & 63;
    const float* xr = x + (size_t)b * (N_INP + 1);
    float v0 = xr[q * 4 + 0], v1 = xr[q * 4 + 1], v2 = xr[q * 4 + 2], v3 = xr[q * 4 + 3];
    ushort4 u = make_ushort4(f2h(v0), f2h(v1), f2h(v2), f2h(v3));
    *reinterpret_cast<ushort4*>(xh + (size_t)b * 256 + q * 4) = u;
    if (q == 0) idx[b] = (int)rintf(xr[N_INP] * 255.0f);
  } else {
    int t = (blockIdx.x - 8192) * 256 + threadIdx.x; // 65536 threads
    float4 a = reinterpret_cast<const float4*>(W1)[t];
    float4 b = reinterpret_cast<const float4*>(W2)[t];
    reinterpret_cast<ushort4*>(w1h)[t] = make_ushort4(f2h(a.x), f2h(a.y), f2h(a.z), f2h(a.w));
    reinterpret_cast<ushort4*>(w2h)[t] = make_ushort4(f2h(b.x), f2h(b.y), f2h(b.z), f2h(b.w));
  }
}

// ---- C[M,N] = epi(A[M,K] @ Bw[N,K]^T + bias), f16 output ----
template <int RELU>
__global__ __launch_bounds__(256, 2) void gemm_bt(
    const ushort* __restrict__ A, const ushort* __restrict__ Bw,
    const float* __restrict__ bias, ushort* __restrict__ C,
    int M, int N, int K, int ntN) {
  __shared__ ushort As[2][128 * 64];
  __shared__ ushort Bs[2][128 * 64];
  const int tid = threadIdx.x;
  const int w = tid >> 6, l = tid & 63;
  // bijective XCD swizzle (grid%8==0 in all our launches)
  int bid = blockIdx.x;
  if (((int)gridDim.x & 7) == 0) {
    int cpx = (int)gridDim.x >> 3;
    bid = (bid & 7) * cpx + (bid >> 3);
  }
  const int tm = bid / ntN, tn = bid % ntN;
  const int wm = w >> 1, wn = w & 1;
  const char* Ab = (const char*)(A + (size_t)tm * 128 * K);
  const char* Bb = (const char*)(Bw + (size_t)tn * 128 * K);
  const int sA = K * 2;
  const int lrow = l >> 3;
  const int lcol = (l & 7) * 16;

  f32x4 acc[4][4];
#pragma unroll
  for (int i = 0; i < 4; ++i)
#pragma unroll
    for (int j = 0; j < 4; ++j) acc[i][j] = {0.f, 0.f, 0.f, 0.f};

  const int nkt = K / 64;
  {
    const char* ga = Ab + lrow * sA + lcol;
    const char* gb = Bb + lrow * sA + lcol;
#pragma unroll
    for (int i = 0; i < 4; ++i) {
      int c = w * 4 + i;
      async_copy16(ga + c * 8 * sA, (char*)&As[0][0] + c * 1024);
      async_copy16(gb + c * 8 * sA, (char*)&Bs[0][0] + c * 1024);
    }
  }
  __syncthreads();

  const int arow = wm * 64 + (l & 15);
  const int brow = wn * 64 + (l & 15);
  const int koff = (l >> 4) * 8;

  for (int kt = 0; kt < nkt; ++kt) {
    const int buf = kt & 1;
    if (kt + 1 < nkt) {
      const char* ga = Ab + (kt + 1) * 128 + lrow * sA + lcol;
      const char* gb = Bb + (kt + 1) * 128 + lrow * sA + lcol;
#pragma unroll
      for (int i = 0; i < 4; ++i) {
        int c = w * 4 + i;
        async_copy16(ga + c * 8 * sA, (char*)&As[buf ^ 1][0] + c * 1024);
        async_copy16(gb + c * 8 * sA, (char*)&Bs[buf ^ 1][0] + c * 1024);
      }
    }
#pragma unroll
    for (int ks = 0; ks < 2; ++ks) {
      f16x8 af[4], bfr[4];
#pragma unroll
      for (int mi = 0; mi < 4; ++mi)
        af[mi] = *(const f16x8*)&As[buf][(arow + mi * 16) * 64 + ks * 32 + koff];
#pragma unroll
      for (int ni = 0; ni < 4; ++ni)
        bfr[ni] = *(const f16x8*)&Bs[buf][(brow + ni * 16) * 64 + ks * 32 + koff];
#pragma unroll
      for (int mi = 0; mi < 4; ++mi)
#pragma unroll
        for (int ni = 0; ni < 4; ++ni)
          acc[mi][ni] = __builtin_amdgcn_mfma_f32_16x16x32_f16(
              af[mi], bfr[ni], acc[mi][ni], 0, 0, 0);
    }
    __syncthreads();
  }

  const int grow0 = tm * 128 + wm * 64 + (l >> 4) * 4;
  const int gcol0 = tn * 128 + wn * 64 + (l & 15);
#pragma unroll
  for (int ni = 0; ni < 4; ++ni) {
    const int col = gcol0 + ni * 16;
    const float bv = bias[col];
#pragma unroll
    for (int mi = 0; mi < 4; ++mi) {
      const int row = grow0 + mi * 16;
#pragma unroll
      for (int r = 0; r < 4; ++r) {
        float v = acc[mi][ni][r] + bv;
        if (RELU) v = fmaxf(v, 0.f);
        C[(size_t)(row + r) * N + col] = f2h(v);
      }
    }
  }
}

// ---- convex fixed-point (100 iters) + gather, PACKED f16 ----
// y-space: y_i <- min(y_i, 0.5*(y_{i-1}+y_{i+1})); result = y.
// 16 lanes/row, 16 feats/lane as 8 f16x2 regs. Shifted stream via alignbit:
//   s_j = (h_j.hi, h_{j+1}.lo);  t_j = s_{j-1}+s_j = both neighbor-sums of h_j
// -> per 2 feats: 1 alignbit + 1 pk_add + 1 pk_mul + 1 pk_min (~0.7x f32 ops).
// Sentinels: f16 +inf in the halo (inf propagates: inf+x=inf, min(y,inf)=y),
// so feats 0 and 255 never update (D boundary rows are zero).
__global__ __launch_bounds__(256) void convex_gather(
    const ushort* __restrict__ xqh, const int* __restrict__ idx,
    float* __restrict__ out) {
  const int l = threadIdx.x & 63;
  const int wv = threadIdx.x >> 6;
  const int q = l & 15;                                // lane within row
  const int b = blockIdx.x * 16 + wv * 4 + (l >> 4);   // global row

  f16x2 h[8];
  {
    const uint4* src = reinterpret_cast<const uint4*>(xqh + (size_t)b * 256 + q * 16);
    uint4 v0 = src[0], v1 = src[1];
    h[0] = as_h2(v0.x); h[1] = as_h2(v0.y); h[2] = as_h2(v0.z); h[3] = as_h2(v0.w);
    h[4] = as_h2(v1.x); h[5] = as_h2(v1.y); h[6] = as_h2(v1.z); h[7] = as_h2(v1.w);
  }
  const int ii = idx[b];
  const int upIdx = ((l - 1) & 63) * 4;
  const int dnIdx = ((l + 1) & 63) * 4;
  const bool fixP = (q == 0);
  const bool fixN = (q == 15);
  const f16x2 halfc = {(_Float16)0.5f, (_Float16)0.5f};

  // prologue halo: (prev y14,y15) and (next y0,y1)
  u32 P = __builtin_amdgcn_ds_bpermute(upIdx, as_u32(h[7]));
  u32 N = __builtin_amdgcn_ds_bpermute(dnIdx, as_u32(h[0]));

#pragma unroll 2
  for (int it = 0; it < N_IT; ++it) {
    u32 Pf = fixP ? 0x7C000000u : P;   // prev.hi = +inf (feat -1 sentinel)
    u32 Nf = fixN ? 0x00007C00u : N;   // next.lo = +inf (feat 16 sentinel)
    // shifted stream from OLD state (alignbit(hi_reg, lo_reg, 16))
    f16x2 sm1 = as_h2(__builtin_amdgcn_alignbit(as_u32(h[0]), Pf, 16));
    f16x2 s0 = as_h2(__builtin_amdgcn_alignbit(as_u32(h[1]), as_u32(h[0]), 16));
    f16x2 s6 = as_h2(__builtin_amdgcn_alignbit(as_u32(h[7]), as_u32(h[6]), 16));
    f16x2 s7 = as_h2(__builtin_amdgcn_alignbit(Nf, as_u32(h[7]), 16));
    f16x2 s1 = as_h2(__builtin_amdgcn_alignbit(as_u32(h[2]), as_u32(h[1]), 16));
    f16x2 s2 = as_h2(__builtin_amdgcn_alignbit(as_u32(h[3]), as_u32(h[2]), 16));
    f16x2 s3 = as_h2(__builtin_amdgcn_alignbit(as_u32(h[4]), as_u32(h[3]), 16));
    f16x2 s4 = as_h2(__builtin_amdgcn_alignbit(as_u32(h[5]), as_u32(h[4]), 16));
    f16x2 s5 = as_h2(__builtin_amdgcn_alignbit(as_u32(h[6]), as_u32(h[5]), 16));
    // boundary regs first, then issue next halo under the interior work
    h[0] = min2(h[0], (sm1 + s0) * halfc);
    h[7] = min2(h[7], (s6 + s7) * halfc);
    P = __builtin_amdgcn_ds_bpermute(upIdx, as_u32(h[7]));
    N = __builtin_amdgcn_ds_bpermute(dnIdx, as_u32(h[0]));
    h[1] = min2(h[1], (s0 + s1) * halfc);
    h[2] = min2(h[2], (s1 + s2) * halfc);
    h[3] = min2(h[3], (s2 + s3) * halfc);
    h[4] = min2(h[4], (s3 + s4) * halfc);
    h[5] = min2(h[5], (s4 + s5) * halfc);
    h[6] = min2(h[6], (s5 + s6) * halfc);
  }

  // gather feature ii: cndmask tree over the 8 b32 regs, pick half, f32 cvt
  u32 r[8];
#pragma unroll
  for (int t = 0; t < 8; ++t) r[t] = as_u32(h[t]);
  const int sr = (ii >> 1) & 7;
#pragma unroll
  for (int step = 4; step >= 1; step >>= 1) {
#pragma unroll
    for (int k = 0; k < 4; ++k) {
      if (k < step) r[k] = (sr & step) ? r[k + step] : r[k];
    }
  }
  ushort hv = (ii & 1) ? (ushort)(r[0] >> 16) : (ushort)(r[0] & 0xffffu);
  float v = (float)__builtin_bit_cast(_Float16, hv);
  v = __shfl(v, (l & ~15) | (ii >> 4));
  if (q == 0) out[b] = v;
}

extern "C" void kernel_launch(void* const* d_in, const int* in_sizes, int n_in,
                              void* d_out, int out_size, void* d_ws, size_t ws_size,
                              hipStream_t stream) {
  const float* x = (const float*)d_in[0];
  const float* W1 = (const float*)d_in[1];
  const float* b1 = (const float*)d_in[2];
  const float* W2 = (const float*)d_in[3];
  const float* b2 = (const float*)d_in[4];
  float* out = (float*)d_out;

  // workspace layout (16B-aligned)
  char* ws = (char*)d_ws;
  ushort* xh  = (ushort*)ws;                    // 16,777,216 B  x f16 [B,256]
  ushort* w1h = (ushort*)(ws + 16777216);       //    524,288 B
  ushort* w2h = (ushort*)(ws + 17301504);       //    524,288 B
  int*    idx = (int*)  (ws + 17825792);        //    131,072 B
  ushort* xqh = (ushort*)(ws + 17956864);       // 16,777,216 B  x_ f16 [B,256]
  ushort* h   = (ushort*)(ws + 34734080);       // chunk*2048 B  h f16 [chunk,1024]

  const size_t fixed = 34734080;
  int chunk = 2048;
  if (ws_size >= fixed + (size_t)32768 * 2048) chunk = 32768;
  else if (ws_size >= fixed + (size_t)16384 * 2048) chunk = 16384;
  else if (ws_size >= fixed + (size_t)8192 * 2048) chunk = 8192;
  else if (ws_size >= fixed + (size_t)4096 * 2048) chunk = 4096;

  prep_kernel<<<8448, 256, 0, stream>>>(x, W1, W2, xh, w1h, w2h, idx);

  for (int m0 = 0; m0 < B_ROWS; m0 += chunk) {
    int curM = (B_ROWS - m0 < chunk) ? (B_ROWS - m0) : chunk;
    dim3 g1((curM / 128) * (N_HID / 128));
    gemm_bt<1><<<g1, 256, 0, stream>>>(xh + (size_t)m0 * 256, w1h, b1, h,
                                       curM, N_HID, N_INP, N_HID / 128);
    dim3 g2((curM / 128) * (NF / 128));
    gemm_bt<0><<<g2, 256, 0, stream>>>(h, w2h, b2, xqh + (size_t)m0 * 256,
                                       curM, NF, N_HID, NF / 128);
  }
  convex_gather<<<B_ROWS / 16, 256, 0, stream>>>(xqh, idx, out);
}